// Round 21
// baseline (5529.554 us; speedup 1.0000x reference)
//
#include <hip/hip_runtime.h>

// r21: dual-chain pipeline (r20) + 2-rows-per-slot (r15) + 256-reg budget.
// r20 audit: VGPR=48 while G1 holds 64 weights -> RA parked weights in AGPRs
// (128-reg budget at launch_bounds(512,4)); v_accvgpr_read per use made each
// MAC ~4cy (busy 1120/slot/SIMD vs 512 FMA-floor). Fix: (a) each slot serves
// 2 rows -> 128 MAC/wave amortizes any per-weight move; (b) launch_bounds
// (512,2) -> 256-reg budget, peak live ~214 fits arch VGPRs -> 2cy MACs.
// 256 blocks x 4 rows (chains A=rows 0-1, B=rows 2-3), 1 block/CU,
// 2 waves/SIMD (1 G1 + 1 G2), both busy every slot. Schedule, single-buffer
// hazard separation, stride-5 partials: verbatim r20 (passed, absmax 0.125).

#define NB 1024
#define ND 64
#define NH 256
#define NBLK 256     // 4 rows per block
#define NTHR 512     // 8 waves: 4x G1 + 4x G2

// LDS float offsets (3328 floats = 13 KB)
#define XBOF(C,W) (((C)<<9) + ((W)<<7))   // xb[2][4][2][64] per-chain per-wave x
#define ABOF(C)   (1024 + ((C)<<9))       // ab[2][2][256]   activations
#define PTOF(C)   (2048 + (C)*640)        // part[2][2][320] stride-5 partials
#define LDS_FL 3328

#define R64(M) M(0) M(1) M(2) M(3) M(4) M(5) M(6) M(7) M(8) M(9) \
  M(10) M(11) M(12) M(13) M(14) M(15) M(16) M(17) M(18) M(19) \
  M(20) M(21) M(22) M(23) M(24) M(25) M(26) M(27) M(28) M(29) \
  M(30) M(31) M(32) M(33) M(34) M(35) M(36) M(37) M(38) M(39) \
  M(40) M(41) M(42) M(43) M(44) M(45) M(46) M(47) M(48) M(49) \
  M(50) M(51) M(52) M(53) M(54) M(55) M(56) M(57) M(58) M(59) \
  M(60) M(61) M(62) M(63)

#define Q16(M) M(0,0,1,2,3) M(1,4,5,6,7) M(2,8,9,10,11) M(3,12,13,14,15) \
  M(4,16,17,18,19) M(5,20,21,22,23) M(6,24,25,26,27) M(7,28,29,30,31) \
  M(8,32,33,34,35) M(9,36,37,38,39) M(10,40,41,42,43) M(11,44,45,46,47) \
  M(12,48,49,50,51) M(13,52,53,54,55) M(14,56,57,58,59) M(15,60,61,62,63)

__device__ __forceinline__ float fast_tanh(float x) {
    float e = __expf(2.0f * x);
    float r = __builtin_amdgcn_rcpf(e + 1.0f);
    return 1.0f - 2.0f * r;
}

// lgkmcnt-only barrier: no vmcnt drain (out stores keep flowing).
#define BSYNC() do {                                             \
    asm volatile("s_waitcnt lgkmcnt(0)" ::: "memory");           \
    __builtin_amdgcn_s_barrier();                                \
    asm volatile("" ::: "memory");                               \
} while (0)

__global__ __launch_bounds__(NTHR, 2)
void node_rk4_kernel(const float* __restrict__ y0,
                     const float* __restrict__ t,
                     const float* W1,
                     const float* b1,
                     const float* W2,
                     const float* b2,
                     float* __restrict__ out,
                     int nsteps)
{
    __shared__ float lds[LDS_FL];
    const int tid = threadIdx.x;
    const int w   = tid >> 6;        // wave 0..7
    const int l   = tid & 63;        // lane

    if (w < 4) {
        // ===== G1: integrate + GEMM1 + tanh; 2 rows per slot =====
        const int j = (w << 6) + l;            // owned hidden unit
        const float b1l = b1[j];
        const float b2l = b2[l];
        #define DW1(i) float w1_##i;
        R64(DW1)
        #define LW1(i) w1_##i = W1[(i) * NH + j];
        R64(LW1)

        float* xbA = lds + XBOF(0, w);
        float* xbB = lds + XBOF(1, w);
        float* abA = lds + ABOF(0);
        float* abB = lds + ABOF(1);
        const float* ptA = lds + PTOF(0);
        const float* ptB = lds + PTOF(1);

        const int row0 = blockIdx.x * 4;
        float yA0 = y0[(row0 + 0) * ND + l], yA1 = y0[(row0 + 1) * ND + l];
        float yB0 = y0[(row0 + 2) * ND + l], yB1 = y0[(row0 + 3) * ND + l];
        float kaA0 = 0.f, kaA1 = 0.f, kaB0 = 0.f, kaB1 = 0.f;
        if (w == 0) {
            out[(size_t)(row0 + 0) * ND + l] = yA0;   // step-0 output
            out[(size_t)(row0 + 1) * ND + l] = yA1;
            out[(size_t)(row0 + 2) * ND + l] = yB0;
            out[(size_t)(row0 + 3) * ND + l] = yB1;
        }
        float dt = 0.f, dt2 = 0.f, dt6 = 0.f;
        size_t obase = 0;

#define G1Q(q,i0,i1,i2,i3) { float4 xa_ = xq0_[q], xb_ = xq1_[q]; \
    h0a = fmaf(w1_##i0, xa_.x, h0a); h0b = fmaf(w1_##i0, xb_.x, h0b); \
    h1a = fmaf(w1_##i1, xa_.y, h1a); h1b = fmaf(w1_##i1, xb_.y, h1b); \
    h0a = fmaf(w1_##i2, xa_.z, h0a); h0b = fmaf(w1_##i2, xb_.z, h0b); \
    h1a = fmaf(w1_##i3, xa_.w, h1a); h1b = fmaf(w1_##i3, xb_.w, h1b); }

// One G1 slot for chain C (rows CB, CB+1): finalize stage ST's k (ST=0:
// init, x=y), RK4-advance x, GEMM1 both rows, tanh, publish a.
#define G1SLOT(C, CB, ST) do {                                        \
    float x0_, x1_;                                                   \
    if ((ST) == 0) { x0_ = y##C##0; x1_ = y##C##1; }                  \
    else {                                                            \
      const float* pr0_ = pt##C + l * 5;                              \
      const float* pr1_ = pt##C + 320 + l * 5;                        \
      float k0_ = ((pr0_[0]+pr0_[1]) + (pr0_[2]+pr0_[3])) + b2l;      \
      float k1_ = ((pr1_[0]+pr1_[1]) + (pr1_[2]+pr1_[3])) + b2l;      \
      if ((ST)==1)      { ka##C##0 = k0_;        ka##C##1 = k1_;      \
          x0_ = fmaf(dt2,k0_,y##C##0); x1_ = fmaf(dt2,k1_,y##C##1); } \
      else if ((ST)==2) { ka##C##0 += 2.0f*k0_;  ka##C##1 += 2.0f*k1_;\
          x0_ = fmaf(dt2,k0_,y##C##0); x1_ = fmaf(dt2,k1_,y##C##1); } \
      else if ((ST)==3) { ka##C##0 += 2.0f*k0_;  ka##C##1 += 2.0f*k1_;\
          x0_ = fmaf(dt,k0_,y##C##0);  x1_ = fmaf(dt,k1_,y##C##1); }  \
      else { y##C##0 = fmaf(dt6, ka##C##0 + k0_, y##C##0);            \
             y##C##1 = fmaf(dt6, ka##C##1 + k1_, y##C##1);            \
             x0_ = y##C##0; x1_ = y##C##1;                            \
             if (w == 0) { out[obase + (CB)*ND + l]       = y##C##0;  \
                           out[obase + ((CB)+1)*ND + l]   = y##C##1; } } \
    }                                                                 \
    xb##C[l] = x0_; xb##C[64 + l] = x1_;                              \
    asm volatile("s_waitcnt lgkmcnt(0)" ::: "memory");                \
    const float4* xq0_ = (const float4*)xb##C;                        \
    const float4* xq1_ = (const float4*)(xb##C + 64);                 \
    float h0a = b1l, h1a = 0.0f, h0b = b1l, h1b = 0.0f;               \
    Q16(G1Q)                                                          \
    ab##C[j]       = fast_tanh(h0a + h1a);                            \
    ab##C[256 + j] = fast_tanh(h0b + h1b);                            \
} while (0)

        G1SLOT(A, 0, 0); BSYNC();     // slot 0
        G1SLOT(B, 2, 0); BSYNC();     // slot 1
        for (int s = 0; s < nsteps; ++s) {
            dt = t[s + 1] - t[s]; dt2 = 0.5f * dt; dt6 = dt * (1.0f / 6.0f);
            obase = (size_t)(s + 1) * (NB * ND) + (size_t)row0 * ND;
            G1SLOT(A, 0, 1); BSYNC();  G1SLOT(B, 2, 1); BSYNC();
            G1SLOT(A, 0, 2); BSYNC();  G1SLOT(B, 2, 2); BSYNC();
            G1SLOT(A, 0, 3); BSYNC();  G1SLOT(B, 2, 3); BSYNC();
            G1SLOT(A, 0, 4); BSYNC();  G1SLOT(B, 2, 4); BSYNC();
        }
    } else {
        // ===== G2: GEMM2 partials; 2 rows per slot =====
        const int jj = w - 4;                  // owned j-slice [64jj,64jj+64)
        #define DW2(i) float w2_##i;
        R64(DW2)
        #define LW2(i) w2_##i = W2[((jj << 6) + (i)) * ND + l];
        R64(LW2)

        const float4* aqA0 = (const float4*)(lds + ABOF(0) + (jj << 6));
        const float4* aqA1 = (const float4*)(lds + ABOF(0) + 256 + (jj << 6));
        const float4* aqB0 = (const float4*)(lds + ABOF(1) + (jj << 6));
        const float4* aqB1 = (const float4*)(lds + ABOF(1) + 256 + (jj << 6));
        float* pwA = lds + PTOF(0);
        float* pwB = lds + PTOF(1);

#define G2Q(q,i0,i1,i2,i3) { float4 aa_ = aq0_[q], ab_ = aq1_[q]; \
    p0a = fmaf(w2_##i0, aa_.x, p0a); p0b = fmaf(w2_##i0, ab_.x, p0b); \
    p1a = fmaf(w2_##i1, aa_.y, p1a); p1b = fmaf(w2_##i1, ab_.y, p1b); \
    p0a = fmaf(w2_##i2, aa_.z, p0a); p0b = fmaf(w2_##i2, ab_.z, p0b); \
    p1a = fmaf(w2_##i3, aa_.w, p1a); p1b = fmaf(w2_##i3, ab_.w, p1b); }

#define G2SLOT(C) do {                                               \
    const float4* aq0_ = aq##C##0; const float4* aq1_ = aq##C##1;    \
    float p0a = 0.f, p1a = 0.f, p0b = 0.f, p1b = 0.f;                \
    Q16(G2Q)                                                         \
    pw##C[l * 5 + jj]       = p0a + p1a;   /* stride-5: free */      \
    pw##C[320 + l * 5 + jj] = p0b + p1b;                             \
} while (0)

        BSYNC();                      // slot 0 (idle)
        G2SLOT(A); BSYNC();           // slot 1: A's k1 partials
        for (int s = 0; s < nsteps; ++s) {
            G2SLOT(B); BSYNC();  G2SLOT(A); BSYNC();
            G2SLOT(B); BSYNC();  G2SLOT(A); BSYNC();
            G2SLOT(B); BSYNC();  G2SLOT(A); BSYNC();
            G2SLOT(B); BSYNC();  G2SLOT(A); BSYNC();
        }
    }
}

extern "C" void kernel_launch(void* const* d_in, const int* in_sizes, int n_in,
                              void* d_out, int out_size, void* d_ws, size_t ws_size,
                              hipStream_t stream) {
    const float* y0 = (const float*)d_in[0];
    const float* t  = (const float*)d_in[1];
    const float* W1 = (const float*)d_in[2];
    const float* b1 = (const float*)d_in[3];
    const float* W2 = (const float*)d_in[4];
    const float* b2 = (const float*)d_in[5];
    float* out = (float*)d_out;
    int nsteps = in_sizes[1] - 1;
    hipLaunchKernelGGL(node_rk4_kernel, dim3(NBLK), dim3(NTHR), 0, stream,
                       y0, t, W1, b1, W2, b2, out, nsteps);
}